// Round 14
// baseline (501.984 us; speedup 1.0000x reference)
//
#include <hip/hip_runtime.h>
#include <hip/hip_bf16.h>
#include <cstdint>
#include <cstddef>

namespace {

constexpr int kB = 2, kLF = 64, kFEAT = 80, kSKIP = 256, kA = 256;
constexpr int kNL = 24, kT4 = 256;
constexpr int kS = 19200;
constexpr int kGR = 64;                 // guard rows (zero history) per batch
constexpr int kXR = kGR + kS;           // 19264 rows per batch in x buffers
constexpr int kK = kNL * 64;            // 1536 skip K
constexpr int kNS = kB * kS;            // 38400
constexpr int kP2 = 72;                 // LDS row stride (ushorts): 144B = 9x16
constexpr int kTile = 80;               // layer t-tile (5 waves x 16)

typedef __attribute__((ext_vector_type(8))) short bf8_t;   // 8 x bf16
typedef __attribute__((ext_vector_type(4))) float f4_t;    // 4 x f32

__device__ inline unsigned short f2bu(float f) {
  __hip_bfloat16 h = __float2bfloat16(f);
  return __builtin_bit_cast(unsigned short, h);
}
__device__ inline float b2f(unsigned short u) {
  unsigned x = (unsigned)u << 16;
  return __builtin_bit_cast(float, x);
}
// tanh(a)*sigmoid(b) with fast exp / fast division
__device__ inline float fast_gate(float a, float b) {
  a = fminf(fmaxf(a, -30.f), 30.f);
  b = fminf(fmaxf(b, -30.f), 30.f);
  const float ea = __expf(-2.f * a);
  const float eb = __expf(-b);
  return (1.f - ea) * __fdividef(1.f, (1.f + ea) * (1.f + eb));
}

// ------- prep: layer weights bf16; skip/head B fragment order; cw transpose ----------
__global__ void prep_kernel(const float* __restrict__ dw, const float* __restrict__ rw,
                            const float* __restrict__ sw, const float* __restrict__ w1,
                            const float* __restrict__ w2, const float* __restrict__ cw,
                            unsigned short* __restrict__ wcb, unsigned short* __restrict__ wrb,
                            unsigned short* __restrict__ swb2, unsigned short* __restrict__ w1f,
                            unsigned short* __restrict__ w2f, float* __restrict__ cwT) {
  int idx = blockIdx.x * 256 + threadIdx.x;
  const int n0 = kNL * 2 * 128 * 64;   // 393216
  const int n1 = (kNL - 1) * 64 * 64;  // 94208
  const int n2 = 256 * kK;             // 393216
  const int n3 = 65536;
  const int n4 = 80 * 3072;            // 245760
  if (idx < n0) {
    int r = idx;
    const int l = r / 16384; r -= l * 16384;
    const int tap = r / 8192; r -= tap * 8192;
    const int o = r / 64; const int h = r - o * 64;
    wcb[idx] = f2bu(dw[((l * 128 + o) * 64 + h) * 2 + tap]);
    return;
  }
  idx -= n0;
  if (idx < n1) { wrb[idx] = f2bu(rw[idx]); return; }
  idx -= n1;
  if (idx < n2) {
    const int q = idx & 31;
    const int rest = idx >> 5;
    const int o = rest & 255;
    const int t = rest >> 8;
    const int kk = t & 1, kb = t >> 1;
    swb2[idx] = f2bu(sw[((size_t)(kb * 256 + o)) * 64 + kk * 32 + q]);
    return;
  }
  idx -= n2;
  if (idx < n3) {
    const int q = idx & 31;
    const int rest = idx >> 5;
    const int a = rest & 255, kk = rest >> 8;
    w1f[idx] = f2bu(w1[a * 256 + kk * 32 + q]);
    return;
  }
  idx -= n3;
  if (idx < n3) {
    const int q = idx & 31;
    const int rest = idx >> 5;
    const int a = rest & 255, kk = rest >> 8;
    w2f[idx] = f2bu(w2[a * 256 + kk * 32 + q]);
    return;
  }
  idx -= n3;
  if (idx < n4) {
    const int c = idx / 3072, o = idx % 3072;
    cwT[idx] = cw[o * 80 + c];
  }
}

// ------- W2[kk*80+cc][o] = sum_c tw[cc][c][kk] * cw[o][c]  (fp32) --------------------
__global__ __launch_bounds__(256) void prep_w2_kernel(const float* __restrict__ tw,
                                                      const float* __restrict__ cwT,
                                                      float* __restrict__ W2) {
  const int o = blockIdx.x * 256 + threadIdx.x;
  const int kk = blockIdx.y;
  __shared__ float twS[80][80];
  for (int i = threadIdx.x; i < 6400; i += 256) twS[i / 80][i % 80] = tw[i * 4 + kk];
  __syncthreads();
  float cwrow[80];
#pragma unroll
  for (int c = 0; c < 80; ++c) cwrow[c] = cwT[c * 3072 + o];
  for (int cc = 0; cc < 80; ++cc) {
    float acc = 0.f;
#pragma unroll
    for (int c = 0; c < 80; ++c) acc += twS[cc][c] * cwrow[c];
    W2[((size_t)(kk * 80 + cc)) * 3072 + o] = acc;
  }
}

// ------- bias2[o] = cb[o] + dbf[o] + sum_c cw[o][c]*tb[c] ----------------------------
__global__ void bias2_kernel(const float* __restrict__ cwT, const float* __restrict__ tb,
                             const float* __restrict__ cb, const float* __restrict__ dbf,
                             float* __restrict__ bias2) {
  const int o = blockIdx.x * 256 + threadIdx.x;
  float acc = cb[o] + dbf[o];
  for (int c = 0; c < 80; ++c) acc += cwT[c * 3072 + o] * tb[c];
  bias2[o] = acc;
}

// ------- cond[b][t4][o] = bias2[o] + sum_cc lf[b][t4>>2][cc] * W2[t4&3][cc][o] -------
__global__ __launch_bounds__(256) void cond_gemm_kernel(
    const float* __restrict__ lf, const float* __restrict__ W2,
    const float* __restrict__ bias2, float* __restrict__ cond) {
  const int o0 = blockIdx.x * 64;
  const int kk = blockIdx.y;
  const int b = blockIdx.z;
  __shared__ float lfS[64][84];
  __shared__ float WS[80][68];
  const int tid = threadIdx.x;
  for (int r = 0; r < 5; ++r) {
    const int f4 = r * 256 + tid;
    const int row = f4 / 20, c4 = (f4 % 20) * 4;
    *reinterpret_cast<float4*>(&lfS[row][c4]) =
        *reinterpret_cast<const float4*>(lf + ((size_t)b * kLF + row) * kFEAT + c4);
  }
  for (int r = 0; r < 5; ++r) {
    const int f4 = r * 256 + tid;
    const int row = f4 >> 4, c4 = (f4 & 15) << 2;
    *reinterpret_cast<float4*>(&WS[row][c4]) =
        *reinterpret_cast<const float4*>(W2 + ((size_t)(kk * 80 + row)) * 3072 + o0 + c4);
  }
  __syncthreads();
  const int tx = tid & 15, oy = tid >> 4;
  float acc[4][4];
#pragma unroll
  for (int j = 0; j < 4; ++j)
#pragma unroll
    for (int r = 0; r < 4; ++r) acc[j][r] = 0.f;
  for (int c = 0; c < 80; ++c) {
    const float4 w = *reinterpret_cast<const float4*>(&WS[c][oy * 4]);
#pragma unroll
    for (int j = 0; j < 4; ++j) {
      const float a = lfS[tx * 4 + j][c];
      acc[j][0] += a * w.x; acc[j][1] += a * w.y;
      acc[j][2] += a * w.z; acc[j][3] += a * w.w;
    }
  }
  const float4 bb = *reinterpret_cast<const float4*>(bias2 + o0 + oy * 4);
#pragma unroll
  for (int j = 0; j < 4; ++j) {
    const int t4 = (tx * 4 + j) * 4 + kk;
    float4 v = make_float4(acc[j][0] + bb.x, acc[j][1] + bb.y,
                           acc[j][2] + bb.z, acc[j][3] + bb.w);
    *reinterpret_cast<float4*>(cond + ((size_t)b * kT4 + t4) * 3072 + o0 + oy * 4) = v;
  }
}

__global__ void bias_sum_kernel(const float* __restrict__ sb, float* __restrict__ bs) {
  const int o = threadIdx.x;
  float s = 0.f;
  for (int i = 0; i < kNL; ++i) s += sb[i * kSKIP + o];
  bs[o] = s;
}

// ---------------- embed: x0[b][gr+t][h] bf16, zero guards in both bufs ----------------
__global__ void embed_kernel(const float* __restrict__ sig, const float* __restrict__ ew,
                             const float* __restrict__ eb, unsigned short* __restrict__ xA,
                             unsigned short* __restrict__ xB) {
  const int idx = blockIdx.x * 256 + threadIdx.x;
  if (idx >= kB * kXR * 8) return;
  const int c8 = (idx & 7) << 3;
  const int row = (idx >> 3) % kXR;
  const int b = idx / (kXR * 8);
  const size_t off = ((size_t)b * kXR + row) * 64 + c8;
  if (row < kGR) {
    uint4 z = {0u, 0u, 0u, 0u};
    *reinterpret_cast<uint4*>(xA + off) = z;
    *reinterpret_cast<uint4*>(xB + off) = z;
  } else {
    const float s = sig[b * kS + row - kGR];
    unsigned short v[8];
#pragma unroll
    for (int q = 0; q < 8; ++q) v[q] = f2bu(s * ew[c8 + q] + eb[c8 + q]);
    *reinterpret_cast<uint4*>(xA + off) = *reinterpret_cast<uint4*>(v);
  }
}

// ------- residual layer v3: tile 80 x 320 thr, 480 blocks (single occupancy round) ---
// LDS 75.5 KB -> 2 blocks/CU; capacity 512 >= 480.
__global__ __launch_bounds__(320) void layer_kernel(
    const unsigned short* __restrict__ x_in, unsigned short* __restrict__ x_out,
    const unsigned short* __restrict__ wcb,  // this layer [2][128][64]
    const unsigned short* __restrict__ wrb,  // this layer [64][64]
    const float* __restrict__ cond, const float* __restrict__ rb,
    unsigned short* __restrict__ gbuf, int layer, int d, int write_x) {
  const int b = blockIdx.y;
  const int t0 = blockIdx.x * kTile;
  const int tid = threadIdx.x;
  const int lane = tid & 63, wv = tid >> 6;     // 5 waves
  const int l15 = lane & 15, l4 = lane >> 4;
  const int nw = wv * 16;

  __shared__ alignas(16) unsigned short Wc[2][128][kP2];   // 36 KB
  __shared__ alignas(16) unsigned short Wr[64][kP2];       // 9 KB
  __shared__ alignas(16) unsigned short xww[112][kP2];     // 15.75 KB (t0-32..t0+79)
  __shared__ alignas(16) unsigned short gt[80][kP2];       // 11.25 KB
  __shared__ float cnd[3][128];
  __shared__ float rbs[64];

  const int c0 = t0 / 75;
  for (int i = tid; i < 384; i += 320) {
    const int ci = i >> 7, o = i & 127;
    int cc = c0 + ci; if (cc > 255) cc = 255;
    cnd[ci][o] = cond[((size_t)b * kT4 + cc) * 3072 + layer * 128 + o];
  }
  if (tid < 64) rbs[tid] = write_x ? rb[tid] : 0.f;
  // weights: 2 taps x 128 rows x 8 chunks = 2048
  for (int f = tid; f < 2048; f += 320) {
    const int row = f >> 3, c8 = (f & 7) << 3;
    *reinterpret_cast<uint4*>(&Wc[row >> 7][row & 127][c8]) =
        *reinterpret_cast<const uint4*>(wcb + (size_t)f * 8);
  }
  if (write_x) {
    for (int f = tid; f < 512; f += 320) {
      const int row = f >> 3, c8 = (f & 7) << 3;
      *reinterpret_cast<uint4*>(&Wr[row][c8]) =
          *reinterpret_cast<const uint4*>(wrb + (size_t)f * 8);
    }
  }
  // x window: 112 rows x 8 chunks = 896 (bf16 raw copy)
  const unsigned short* xwin = x_in + ((size_t)b * kXR + kGR + t0 - 32) * 64;
  for (int f = tid; f < 896; f += 320) {
    const int row = f >> 3, c8 = (f & 7) << 3;
    *reinterpret_cast<uint4*>(&xww[row][c8]) =
        *reinterpret_cast<const uint4*>(xwin + (size_t)f * 8);
  }
  __syncthreads();

  f4_t acc[8];
#pragma unroll
  for (int i = 0; i < 8; ++i) acc[i] = (f4_t){0.f, 0.f, 0.f, 0.f};
#pragma unroll
  for (int kk = 0; kk < 2; ++kk) {
    const int ko = kk * 32 + l4 * 8;
    const bf8_t b1 = *reinterpret_cast<const bf8_t*>(&xww[32 + nw + l15][ko]);       // tap1
    const bf8_t b0 = *reinterpret_cast<const bf8_t*>(&xww[32 - d + nw + l15][ko]);   // tap0
#pragma unroll
    for (int mi = 0; mi < 8; ++mi) {
      const bf8_t a1 = *reinterpret_cast<const bf8_t*>(&Wc[1][mi * 16 + l15][ko]);
      acc[mi] = __builtin_amdgcn_mfma_f32_16x16x32_bf16(a1, b1, acc[mi], 0, 0, 0);
      const bf8_t a0 = *reinterpret_cast<const bf8_t*>(&Wc[0][mi * 16 + l15][ko]);
      acc[mi] = __builtin_amdgcn_mfma_f32_16x16x32_bf16(a0, b0, acc[mi], 0, 0, 0);
    }
  }

  // gate -> gt (bf16, [n][h]); own-lane row only
  const int t_lane = t0 + nw + l15;
  const int ci = (t_lane >= (c0 + 1) * 75 ? 1 : 0) + (t_lane >= (c0 + 2) * 75 ? 1 : 0);
  const int grow = nw + l15;
#pragma unroll
  for (int mi = 0; mi < 4; ++mi) {
    float gg[4];
#pragma unroll
    for (int r = 0; r < 4; ++r) {
      const int olo = mi * 16 + l4 * 4 + r;
      gg[r] = fast_gate(acc[mi][r] + cnd[ci][olo], acc[mi + 4][r] + cnd[ci][olo + 64]);
    }
    const int hb = mi * 16 + l4 * 4;
    *reinterpret_cast<unsigned int*>(&gt[grow][hb]) =
        (unsigned)f2bu(gg[0]) | ((unsigned)f2bu(gg[1]) << 16);
    *reinterpret_cast<unsigned int*>(&gt[grow][hb + 2]) =
        (unsigned)f2bu(gg[2]) | ((unsigned)f2bu(gg[3]) << 16);
  }

  // g -> gbuf (wave-private rows nw..nw+15), PRE-SWIZZLED chunk slot = c ^ (n&7)
  {
    unsigned short* gb = gbuf + ((size_t)layer * kNS + b * kS + t0) * 64;
#pragma unroll
    for (int r = 0; r < 2; ++r) {
      const int q = lane * 2 + r;
      const int row = nw + (q >> 3);
      const int c = q & 7;
      const int cs = c ^ (row & 7);
      *reinterpret_cast<uint4*>(gb + (size_t)row * 64 + (cs << 3)) =
          *reinterpret_cast<const uint4*>(&gt[row][c << 3]);
    }
  }

  if (write_x) {
    // res GEMM from gt (own-lane row)
    f4_t accr[4];
#pragma unroll
    for (int i = 0; i < 4; ++i) accr[i] = (f4_t){0.f, 0.f, 0.f, 0.f};
#pragma unroll
    for (int kk = 0; kk < 2; ++kk) {
      const int ko = kk * 32 + l4 * 8;
      const bf8_t bfr = *reinterpret_cast<const bf8_t*>(&gt[grow][ko]);
#pragma unroll
      for (int mi = 0; mi < 4; ++mi) {
        const bf8_t afr = *reinterpret_cast<const bf8_t*>(&Wr[mi * 16 + l15][ko]);
        accr[mi] = __builtin_amdgcn_mfma_f32_16x16x32_bf16(afr, bfr, accr[mi], 0, 0, 0);
      }
    }
    // x' = accr + rb + x_in -> overwrite own gt row (g already flushed to gbuf)
#pragma unroll
    for (int mi = 0; mi < 4; ++mi) {
      const int h0 = mi * 16 + l4 * 4;
      const unsigned u01 = *reinterpret_cast<const unsigned*>(&xww[32 + grow][h0]);
      const unsigned u23 = *reinterpret_cast<const unsigned*>(&xww[32 + grow][h0 + 2]);
      const float x0 = accr[mi][0] + rbs[h0 + 0] + b2f((unsigned short)(u01 & 0xffffu));
      const float x1 = accr[mi][1] + rbs[h0 + 1] + b2f((unsigned short)(u01 >> 16));
      const float x2 = accr[mi][2] + rbs[h0 + 2] + b2f((unsigned short)(u23 & 0xffffu));
      const float x3 = accr[mi][3] + rbs[h0 + 3] + b2f((unsigned short)(u23 >> 16));
      *reinterpret_cast<unsigned*>(&gt[grow][h0]) =
          (unsigned)f2bu(x0) | ((unsigned)f2bu(x1) << 16);
      *reinterpret_cast<unsigned*>(&gt[grow][h0 + 2]) =
          (unsigned)f2bu(x2) | ((unsigned)f2bu(x3) << 16);
    }
    // x_out write (wave-private rows), 2KB contiguous per wave
    unsigned short* xob = x_out + ((size_t)b * kXR + kGR + t0) * 64;
#pragma unroll
    for (int r = 0; r < 2; ++r) {
      const int q = lane * 2 + r;
      const int row = nw + (q >> 3), c8 = (q & 7) << 3;
      *reinterpret_cast<uint4*>(xob + (size_t)row * 64 + c8) =
          *reinterpret_cast<const uint4*>(&gt[row][c8]);
    }
  }
}

// ------- skip GEMM v4 (unchanged): 600x512, 64n x 256o, coalesced fragment B ---------
__global__ __launch_bounds__(512) void skip_kernel(
    const unsigned short* __restrict__ gbuf, const unsigned short* __restrict__ swb2,
    const float* __restrict__ bs, unsigned short* __restrict__ skipb) {
  const int n0 = blockIdx.x * 64;
  __shared__ alignas(16) unsigned short Ag[2][128][64];
  const int tid = threadIdx.x, lane = tid & 63, wv = tid >> 6;
  const int l15 = lane & 15, l4 = lane >> 4;
  const int ow = wv * 32;
  f4_t acc[4][2];
#pragma unroll
  for (int i = 0; i < 4; ++i)
#pragma unroll
    for (int j = 0; j < 2; ++j) acc[i][j] = (f4_t){0.f, 0.f, 0.f, 0.f};

#define STAGE2(kb2, buf)                                                               \
  {                                                                                    \
    const unsigned short* s0 =                                                         \
        gbuf + ((size_t)((kb2)*2) * kNS + n0) * 64 + (size_t)tid * 8;                  \
    const unsigned short* s1 =                                                         \
        gbuf + ((size_t)((kb2)*2 + 1) * kNS + n0) * 64 + (size_t)tid * 8;              \
    __builtin_amdgcn_global_load_lds(                                                  \
        (const __attribute__((address_space(1))) unsigned int*)s0,                     \
        (__attribute__((address_space(3))) unsigned int*)(&Ag[buf][wv * 8][0]),        \
        16, 0, 0);                                                                     \
    __builtin_amdgcn_global_load_lds(                                                  \
        (const __attribute__((address_space(1))) unsigned int*)s1,                     \
        (__attribute__((address_space(3))) unsigned int*)(&Ag[buf][64 + wv * 8][0]),   \
        16, 0, 0);                                                                     \
  }

  STAGE2(0, 0);
  for (int kb2 = 0; kb2 < 12; ++kb2) {
    __syncthreads();
    if (kb2 < 11) STAGE2(kb2 + 1, (kb2 + 1) & 1);
    const int bi = kb2 & 1;
#pragma unroll
    for (int sub = 0; sub < 2; ++sub) {
      const int kb = kb2 * 2 + sub;
#pragma unroll
      for (int kk = 0; kk < 2; ++kk) {
        bf8_t afr[4], bfr[2];
#pragma unroll
        for (int i = 0; i < 4; ++i) {
          const int row = i * 16 + l15;
          const int slot = (kk * 4 + l4) ^ (row & 7);
          afr[i] = *reinterpret_cast<const bf8_t*>(&Ag[bi][sub * 64 + row][slot << 3]);
        }
#pragma unroll
        for (int j = 0; j < 2; ++j)
          bfr[j] = *reinterpret_cast<const bf8_t*>(
              swb2 + ((size_t)(kb * 2 + kk) * 256 + ow + j * 16 + l15) * 32 + l4 * 8);
#pragma unroll
        for (int mi = 0; mi < 4; ++mi)
#pragma unroll
          for (int ni = 0; ni < 2; ++ni)
            acc[mi][ni] = __builtin_amdgcn_mfma_f32_16x16x32_bf16(afr[mi], bfr[ni],
                                                                  acc[mi][ni], 0, 0, 0);
      }
    }
  }
#undef STAGE2
#pragma unroll
  for (int mi = 0; mi < 4; ++mi)
#pragma unroll
    for (int ni = 0; ni < 2; ++ni) {
      const int o = ow + ni * 16 + l15;
      const float bo = bs[o];
#pragma unroll
      for (int r = 0; r < 4; ++r) {
        const int n = n0 + mi * 16 + l4 * 4 + r;
        skipb[(size_t)n * 256 + o] = f2bu(acc[mi][ni][r] + bo);
      }
    }
}

// ---------------- head (unchanged): relu -> W1 -> relu -> W2 -> log_softmax ----------
__device__ inline unsigned int relu2(unsigned int u) {
  const unsigned lo = (u & 0x8000u) ? 0u : (u & 0xFFFFu);
  const unsigned hi = (u & 0x80000000u) ? 0u : (u & 0xFFFF0000u);
  return lo | hi;
}

__global__ __launch_bounds__(256) void head_kernel(
    const unsigned short* __restrict__ skipb, const unsigned short* __restrict__ w1f,
    const unsigned short* __restrict__ w2f, float* __restrict__ out) {
  const int b = blockIdx.y;
  const int t0 = blockIdx.x * 32;
  const int n0 = b * kS + t0;
  __shared__ __align__(16) char smem[16896 * 2];
  __shared__ float lsa[32];
  unsigned short (*A1)[264] = reinterpret_cast<unsigned short(*)[264]>(smem);
  unsigned short (*H1)[264] = reinterpret_cast<unsigned short(*)[264]>(smem + 16896);
  float (*LG)[260] = reinterpret_cast<float(*)[260]>(smem);

  const int tid = threadIdx.x, lane = tid & 63, wv = tid >> 6;
  const int l15 = lane & 15, l4 = lane >> 4;
  for (int r = 0; r < 4; ++r) {
    const int ch = r * 256 + tid;
    const int row = ch >> 5, c8 = (ch & 31) << 3;
    uint4 v = *reinterpret_cast<const uint4*>(skipb + (size_t)(n0 + row) * 256 + c8);
    v.x = relu2(v.x); v.y = relu2(v.y); v.z = relu2(v.z); v.w = relu2(v.w);
    *reinterpret_cast<uint4*>(&A1[row][c8]) = v;
  }
  __syncthreads();
  f4_t a1[2][4];
#pragma unroll
  for (int i = 0; i < 2; ++i)
#pragma unroll
    for (int j = 0; j < 4; ++j) a1[i][j] = (f4_t){0.f, 0.f, 0.f, 0.f};
  for (int kk = 0; kk < 8; ++kk) {
    const int ko = kk * 32 + l4 * 8;
    bf8_t afr[2], bfr[4];
#pragma unroll
    for (int i = 0; i < 2; ++i)
      afr[i] = *reinterpret_cast<const bf8_t*>(&A1[i * 16 + l15][ko]);
#pragma unroll
    for (int j = 0; j < 4; ++j)
      bfr[j] = *reinterpret_cast<const bf8_t*>(
          w1f + ((size_t)kk * 256 + wv * 64 + j * 16 + l15) * 32 + l4 * 8);
#pragma unroll
    for (int mi = 0; mi < 2; ++mi)
#pragma unroll
      for (int ni = 0; ni < 4; ++ni)
        a1[mi][ni] = __builtin_amdgcn_mfma_f32_16x16x32_bf16(afr[mi], bfr[ni],
                                                             a1[mi][ni], 0, 0, 0);
  }
#pragma unroll
  for (int mi = 0; mi < 2; ++mi)
#pragma unroll
    for (int ni = 0; ni < 4; ++ni)
#pragma unroll
      for (int r = 0; r < 4; ++r)
        H1[mi * 16 + l4 * 4 + r][wv * 64 + ni * 16 + l15] =
            f2bu(fmaxf(a1[mi][ni][r], 0.f));
  __syncthreads();
  f4_t a2[2][4];
#pragma unroll
  for (int i = 0; i < 2; ++i)
#pragma unroll
    for (int j = 0; j < 4; ++j) a2[i][j] = (f4_t){0.f, 0.f, 0.f, 0.f};
  for (int kk = 0; kk < 8; ++kk) {
    const int ko = kk * 32 + l4 * 8;
    bf8_t afr[2], bfr[4];
#pragma unroll
    for (int i = 0; i < 2; ++i)
      afr[i] = *reinterpret_cast<const bf8_t*>(&H1[i * 16 + l15][ko]);
#pragma unroll
    for (int j = 0; j < 4; ++j)
      bfr[j] = *reinterpret_cast<const bf8_t*>(
          w2f + ((size_t)kk * 256 + wv * 64 + j * 16 + l15) * 32 + l4 * 8);
#pragma unroll
    for (int mi = 0; mi < 2; ++mi)
#pragma unroll
      for (int ni = 0; ni < 4; ++ni)
        a2[mi][ni] = __builtin_amdgcn_mfma_f32_16x16x32_bf16(afr[mi], bfr[ni],
                                                             a2[mi][ni], 0, 0, 0);
  }
  __syncthreads();
#pragma unroll
  for (int mi = 0; mi < 2; ++mi)
#pragma unroll
    for (int ni = 0; ni < 4; ++ni)
#pragma unroll
      for (int r = 0; r < 4; ++r)
        LG[mi * 16 + l4 * 4 + r][wv * 64 + ni * 16 + l15] = a2[mi][ni][r];
  __syncthreads();
  const int rn = tid >> 3, s = tid & 7;
  float m = -3.4e38f;
  for (int a = s; a < 256; a += 8) m = fmaxf(m, LG[rn][a]);
  m = fmaxf(m, __shfl_xor(m, 1));
  m = fmaxf(m, __shfl_xor(m, 2));
  m = fmaxf(m, __shfl_xor(m, 4));
  float sum = 0.f;
  for (int a = s; a < 256; a += 8) sum += __expf(LG[rn][a] - m);
  sum += __shfl_xor(sum, 1);
  sum += __shfl_xor(sum, 2);
  sum += __shfl_xor(sum, 4);
  if (s == 0) lsa[rn] = m + __logf(sum);
  __syncthreads();
  float* ob = out + (size_t)b * kA * kS + t0;
  for (int q = 0; q < 8; ++q) {
    const int a = q * 32 + (tid >> 3);
    const int t4 = (tid & 7) * 4;
    float4 v;
    v.x = LG[t4 + 0][a] - lsa[t4 + 0];
    v.y = LG[t4 + 1][a] - lsa[t4 + 1];
    v.z = LG[t4 + 2][a] - lsa[t4 + 2];
    v.w = LG[t4 + 3][a] - lsa[t4 + 3];
    *reinterpret_cast<float4*>(ob + (size_t)a * kS + t4) = v;
  }
}

}  // namespace

extern "C" void kernel_launch(void* const* d_in, const int* in_sizes, int n_in,
                              void* d_out, int out_size, void* d_ws, size_t ws_size,
                              hipStream_t stream) {
  const float* lf  = (const float*)d_in[0];
  const float* sig = (const float*)d_in[1];
  const float* ew  = (const float*)d_in[2];
  const float* eb  = (const float*)d_in[3];
  const float* tw  = (const float*)d_in[4];
  const float* tb  = (const float*)d_in[5];
  const float* cw  = (const float*)d_in[6];
  const float* cb  = (const float*)d_in[7];
  const float* dw  = (const float*)d_in[8];
  const float* dbf = (const float*)d_in[9];
  const float* rw  = (const float*)d_in[10];
  const float* rb  = (const float*)d_in[11];
  const float* sw  = (const float*)d_in[12];
  const float* sb  = (const float*)d_in[13];
  const float* w1  = (const float*)d_in[14];
  const float* w2  = (const float*)d_in[15];
  float* out = (float*)d_out;

  char* p = (char*)d_ws;
  float* cond = (float*)p;            p += (size_t)kB * kT4 * 3072 * 4;
  unsigned short* xA = (unsigned short*)p;    p += (size_t)kB * kXR * 64 * 2;
  unsigned short* xB = (unsigned short*)p;    p += (size_t)kB * kXR * 64 * 2;
  unsigned short* gbuf = (unsigned short*)p;  p += (size_t)kNL * kNS * 64 * 2;
  unsigned short* skipb = (unsigned short*)p; p += (size_t)kNS * 256 * 2;
  unsigned short* wcb = (unsigned short*)p;   p += (size_t)kNL * 2 * 128 * 64 * 2;
  unsigned short* wrb = (unsigned short*)p;   p += (size_t)(kNL - 1) * 64 * 64 * 2;
  unsigned short* swb2 = (unsigned short*)p;  p += (size_t)256 * kK * 2;
  unsigned short* w1f = (unsigned short*)p;   p += (size_t)256 * 256 * 2;
  unsigned short* w2f = (unsigned short*)p;   p += (size_t)256 * 256 * 2;
  float* bs = (float*)p;              p += 1024;
  float* cwT = (float*)p;             p += (size_t)80 * 3072 * 4;
  float* W2 = (float*)p;              p += (size_t)4 * 80 * 3072 * 4;
  float* bias2 = (float*)p;           p += (size_t)3072 * 4;

  const int prep_n = 393216 + 94208 + 393216 + 65536 + 65536 + 245760;
  prep_kernel<<<(prep_n + 255) / 256, 256, 0, stream>>>(dw, rw, sw, w1, w2, cw,
                                                        wcb, wrb, swb2, w1f, w2f, cwT);
  prep_w2_kernel<<<dim3(12, 4), 256, 0, stream>>>(tw, cwT, W2);
  bias2_kernel<<<12, 256, 0, stream>>>(cwT, tb, cb, dbf, bias2);
  cond_gemm_kernel<<<dim3(48, 4, 2), 256, 0, stream>>>(lf, W2, bias2, cond);
  bias_sum_kernel<<<1, 256, 0, stream>>>(sb, bs);
  embed_kernel<<<(kB * kXR * 8 + 255) / 256, 256, 0, stream>>>(sig, ew, eb, xA, xB);

  unsigned short* xcur = xA;
  unsigned short* xnxt = xB;
  for (int l = 0; l < kNL; ++l) {
    const int d = 1 << (l % 6);
    const int wx = (l < kNL - 1) ? 1 : 0;
    layer_kernel<<<dim3(kS / kTile, kB), 320, 0, stream>>>(
        xcur, xnxt, wcb + (size_t)l * 16384, wrb + (size_t)(wx ? l : 0) * 4096,
        cond, rb + (size_t)(wx ? l : 0) * 64, gbuf, l, d, wx);
    if (wx) { unsigned short* tmp = xcur; xcur = xnxt; xnxt = tmp; }
  }
  skip_kernel<<<600, 512, 0, stream>>>(gbuf, swb2, bs, skipb);
  head_kernel<<<dim3(600, 2), 256, 0, stream>>>(skipb, w1f, w2f, out);
}

// Round 15
// 386.707 us; speedup vs baseline: 1.2981x; 1.2981x over previous
//
#include <hip/hip_runtime.h>
#include <hip/hip_bf16.h>
#include <cstdint>
#include <cstddef>

namespace {

constexpr int kB = 2, kLF = 64, kFEAT = 80, kSKIP = 256, kA = 256;
constexpr int kNL = 24, kT4 = 256;
constexpr int kS = 19200;
constexpr int kGR = 64;                 // guard rows (zero history) per batch
constexpr int kXR = kGR + kS;           // 19264 rows per batch in x buffers
constexpr int kK = kNL * 64;            // 1536 skip K
constexpr int kNS = kB * kS;            // 38400

typedef __attribute__((ext_vector_type(8))) short bf8_t;   // 8 x bf16
typedef __attribute__((ext_vector_type(4))) float f4_t;    // 4 x f32

__device__ inline unsigned short f2bu(float f) {
  __hip_bfloat16 h = __float2bfloat16(f);
  return __builtin_bit_cast(unsigned short, h);
}
__device__ inline float b2f(unsigned short u) {
  unsigned x = (unsigned)u << 16;
  return __builtin_bit_cast(float, x);
}
// tanh(a)*sigmoid(b) with fast exp / fast division
__device__ inline float fast_gate(float a, float b) {
  a = fminf(fmaxf(a, -30.f), 30.f);
  b = fminf(fmaxf(b, -30.f), 30.f);
  const float ea = __expf(-2.f * a);
  const float eb = __expf(-b);
  return (1.f - ea) * __fdividef(1.f, (1.f + ea) * (1.f + eb));
}

// ------- prep: conv weights bf16 (LDS layout); res/skip/head frag order; cw transpose -
// wcb[l][tap][o=128][h=64]      (conv, LDS-staged swizzled in layer)
// wrf[l][(kk*64+o)*32+q]        (res A-frags, register-loaded)
// swb2[((kb*2+kk)*256+o)*32+q]  (skip B-frags)
// w1f/w2f[(kk*256+a)*32+q]      (head B-frags)
// cwT[c*3072+o] = cw[o*80+c]    (fp32, for W2 build)
__global__ void prep_kernel(const float* __restrict__ dw, const float* __restrict__ rw,
                            const float* __restrict__ sw, const float* __restrict__ w1,
                            const float* __restrict__ w2, const float* __restrict__ cw,
                            unsigned short* __restrict__ wcb, unsigned short* __restrict__ wrf,
                            unsigned short* __restrict__ swb2, unsigned short* __restrict__ w1f,
                            unsigned short* __restrict__ w2f, float* __restrict__ cwT) {
  int idx = blockIdx.x * 256 + threadIdx.x;
  const int n0 = kNL * 2 * 128 * 64;   // 393216
  const int n1 = (kNL - 1) * 64 * 64;  // 94208
  const int n2 = 256 * kK;             // 393216
  const int n3 = 65536;
  const int n4 = 80 * 3072;            // 245760
  if (idx < n0) {
    int r = idx;
    const int l = r / 16384; r -= l * 16384;
    const int tap = r / 8192; r -= tap * 8192;
    const int o = r / 64; const int h = r - o * 64;
    wcb[idx] = f2bu(dw[((l * 128 + o) * 64 + h) * 2 + tap]);
    return;
  }
  idx -= n0;
  if (idx < n1) {
    const int l = idx / 4096, r = idx % 4096;
    const int q = r & 31;
    const int rest = r >> 5;
    const int o = rest & 63;
    const int kk = rest >> 6;
    wrf[idx] = f2bu(rw[(l * 64 + o) * 64 + kk * 32 + q]);
    return;
  }
  idx -= n1;
  if (idx < n2) {
    const int q = idx & 31;
    const int rest = idx >> 5;
    const int o = rest & 255;
    const int t = rest >> 8;
    const int kk = t & 1, kb = t >> 1;
    swb2[idx] = f2bu(sw[((size_t)(kb * 256 + o)) * 64 + kk * 32 + q]);
    return;
  }
  idx -= n2;
  if (idx < n3) {
    const int q = idx & 31;
    const int rest = idx >> 5;
    const int a = rest & 255, kk = rest >> 8;
    w1f[idx] = f2bu(w1[a * 256 + kk * 32 + q]);
    return;
  }
  idx -= n3;
  if (idx < n3) {
    const int q = idx & 31;
    const int rest = idx >> 5;
    const int a = rest & 255, kk = rest >> 8;
    w2f[idx] = f2bu(w2[a * 256 + kk * 32 + q]);
    return;
  }
  idx -= n3;
  if (idx < n4) {
    const int c = idx / 3072, o = idx % 3072;
    cwT[idx] = cw[o * 80 + c];
  }
}

// ------- W2[kk*80+cc][o] = sum_c tw[cc][c][kk] * cw[o][c]  (fp32) --------------------
__global__ __launch_bounds__(256) void prep_w2_kernel(const float* __restrict__ tw,
                                                      const float* __restrict__ cwT,
                                                      float* __restrict__ W2) {
  const int o = blockIdx.x * 256 + threadIdx.x;
  const int kk = blockIdx.y;
  __shared__ float twS[80][80];
  for (int i = threadIdx.x; i < 6400; i += 256) twS[i / 80][i % 80] = tw[i * 4 + kk];
  __syncthreads();
  float cwrow[80];
#pragma unroll
  for (int c = 0; c < 80; ++c) cwrow[c] = cwT[c * 3072 + o];
  for (int cc = 0; cc < 80; ++cc) {
    float acc = 0.f;
#pragma unroll
    for (int c = 0; c < 80; ++c) acc += twS[cc][c] * cwrow[c];
    W2[((size_t)(kk * 80 + cc)) * 3072 + o] = acc;
  }
}

// ------- bias2[o] = cb[o] + dbf[o] + sum_c cw[o][c]*tb[c] ----------------------------
__global__ void bias2_kernel(const float* __restrict__ cwT, const float* __restrict__ tb,
                             const float* __restrict__ cb, const float* __restrict__ dbf,
                             float* __restrict__ bias2) {
  const int o = blockIdx.x * 256 + threadIdx.x;
  float acc = cb[o] + dbf[o];
  for (int c = 0; c < 80; ++c) acc += cwT[c * 3072 + o] * tb[c];
  bias2[o] = acc;
}

// ------- cond[b][t4][o] = bias2[o] + sum_cc lf[b][t4>>2][cc] * W2[t4&3][cc][o] -------
__global__ __launch_bounds__(256) void cond_gemm_kernel(
    const float* __restrict__ lf, const float* __restrict__ W2,
    const float* __restrict__ bias2, float* __restrict__ cond) {
  const int o0 = blockIdx.x * 64;
  const int kk = blockIdx.y;
  const int b = blockIdx.z;
  __shared__ float lfS[64][84];
  __shared__ float WS[80][68];
  const int tid = threadIdx.x;
  for (int r = 0; r < 5; ++r) {
    const int f4 = r * 256 + tid;
    const int row = f4 / 20, c4 = (f4 % 20) * 4;
    *reinterpret_cast<float4*>(&lfS[row][c4]) =
        *reinterpret_cast<const float4*>(lf + ((size_t)b * kLF + row) * kFEAT + c4);
  }
  for (int r = 0; r < 5; ++r) {
    const int f4 = r * 256 + tid;
    const int row = f4 >> 4, c4 = (f4 & 15) << 2;
    *reinterpret_cast<float4*>(&WS[row][c4]) =
        *reinterpret_cast<const float4*>(W2 + ((size_t)(kk * 80 + row)) * 3072 + o0 + c4);
  }
  __syncthreads();
  const int tx = tid & 15, oy = tid >> 4;
  float acc[4][4];
#pragma unroll
  for (int j = 0; j < 4; ++j)
#pragma unroll
    for (int r = 0; r < 4; ++r) acc[j][r] = 0.f;
  for (int c = 0; c < 80; ++c) {
    const float4 w = *reinterpret_cast<const float4*>(&WS[c][oy * 4]);
#pragma unroll
    for (int j = 0; j < 4; ++j) {
      const float a = lfS[tx * 4 + j][c];
      acc[j][0] += a * w.x; acc[j][1] += a * w.y;
      acc[j][2] += a * w.z; acc[j][3] += a * w.w;
    }
  }
  const float4 bb = *reinterpret_cast<const float4*>(bias2 + o0 + oy * 4);
#pragma unroll
  for (int j = 0; j < 4; ++j) {
    const int t4 = (tx * 4 + j) * 4 + kk;
    float4 v = make_float4(acc[j][0] + bb.x, acc[j][1] + bb.y,
                           acc[j][2] + bb.z, acc[j][3] + bb.w);
    *reinterpret_cast<float4*>(cond + ((size_t)b * kT4 + t4) * 3072 + o0 + oy * 4) = v;
  }
}

__global__ void bias_sum_kernel(const float* __restrict__ sb, float* __restrict__ bs) {
  const int o = threadIdx.x;
  float s = 0.f;
  for (int i = 0; i < kNL; ++i) s += sb[i * kSKIP + o];
  bs[o] = s;
}

// ---------------- embed: x0[b][gr+t][h] bf16, zero guards in both bufs ----------------
__global__ void embed_kernel(const float* __restrict__ sig, const float* __restrict__ ew,
                             const float* __restrict__ eb, unsigned short* __restrict__ xA,
                             unsigned short* __restrict__ xB) {
  const int idx = blockIdx.x * 256 + threadIdx.x;
  if (idx >= kB * kXR * 8) return;
  const int c8 = (idx & 7) << 3;
  const int row = (idx >> 3) % kXR;
  const int b = idx / (kXR * 8);
  const size_t off = ((size_t)b * kXR + row) * 64 + c8;
  if (row < kGR) {
    uint4 z = {0u, 0u, 0u, 0u};
    *reinterpret_cast<uint4*>(xA + off) = z;
    *reinterpret_cast<uint4*>(xB + off) = z;
  } else {
    const float s = sig[b * kS + row - kGR];
    unsigned short v[8];
#pragma unroll
    for (int q = 0; q < 8; ++q) v[q] = f2bu(s * ew[c8 + q] + eb[c8 + q]);
    *reinterpret_cast<uint4*>(xA + off) = *reinterpret_cast<uint4*>(v);
  }
}

// ------- residual layer v4: 64-t tile, 256 thr, 600 blocks; 53.3KB LDS -> 3 blk/CU ---
// LDS tiles stride-64 ushorts, XOR chunk swizzle slot = c ^ (row&7) (skip-proven).
// Res weights + rb in registers (fragment-order, loaded at entry, off critical path).
__global__ __launch_bounds__(256, 3) void layer_kernel(
    const unsigned short* __restrict__ x_in, unsigned short* __restrict__ x_out,
    const unsigned short* __restrict__ wcb,  // this layer [2][128][64]
    const unsigned short* __restrict__ wrf,  // this layer frag order [(kk*64+o)*32+q]
    const float* __restrict__ cond, const float* __restrict__ rb,
    unsigned short* __restrict__ gbuf, int layer, int d, int write_x) {
  const int b = blockIdx.y;
  const int t0 = blockIdx.x * 64;
  const int tid = threadIdx.x;
  const int lane = tid & 63, wv = tid >> 6;
  const int l15 = lane & 15, l4 = lane >> 4;
  const int nw = wv * 16;

  __shared__ alignas(16) unsigned short WcS[256 * 64];   // 32 KB (rows tap*128+o)
  __shared__ alignas(16) unsigned short xwS[96 * 64];    // 12 KB (rows t0-32..t0+63)
  __shared__ alignas(16) unsigned short gtS[64 * 64];    // 8 KB
  __shared__ float cnd[2][128];                          // 1 KB

  // res weights -> registers (coalesced 1KB/wave fragment loads, off critical path)
  bf8_t wrr[2][4];
  float4 rbv[4];
  if (write_x) {
#pragma unroll
    for (int kk = 0; kk < 2; ++kk)
#pragma unroll
      for (int mi = 0; mi < 4; ++mi)
        wrr[kk][mi] = *reinterpret_cast<const bf8_t*>(
            wrf + ((size_t)(kk * 64 + mi * 16 + l15)) * 32 + l4 * 8);
#pragma unroll
    for (int mi = 0; mi < 4; ++mi)
      rbv[mi] = *reinterpret_cast<const float4*>(rb + mi * 16 + l4 * 4);
  }

  const int c0 = t0 / 75;
  {
    const int ci = tid >> 7, o = tid & 127;
    int cc = c0 + ci; if (cc > 255) cc = 255;
    cnd[ci][o] = cond[((size_t)b * kT4 + cc) * 3072 + layer * 128 + o];
  }
  // Wc: 256 rows x 8 chunks = 2048, staged swizzled
  for (int r = 0; r < 8; ++r) {
    const int f = r * 256 + tid;
    const int row = f >> 3, c = f & 7, slot = c ^ (row & 7);
    *reinterpret_cast<uint4*>(&WcS[row * 64 + slot * 8]) =
        *reinterpret_cast<const uint4*>(wcb + (size_t)f * 8);
  }
  // x window: 96 rows x 8 chunks = 768, staged swizzled
  const unsigned short* xwin = x_in + ((size_t)b * kXR + kGR + t0 - 32) * 64;
  for (int r = 0; r < 3; ++r) {
    const int f = r * 256 + tid;
    const int row = f >> 3, c = f & 7, slot = c ^ (row & 7);
    *reinterpret_cast<uint4*>(&xwS[row * 64 + slot * 8]) =
        *reinterpret_cast<const uint4*>(xwin + (size_t)f * 8);
  }
  __syncthreads();

  // conv MFMA (swizzled reads; each lane's 16B slot = chunk ck of its row)
  f4_t acc[8];
#pragma unroll
  for (int i = 0; i < 8; ++i) acc[i] = (f4_t){0.f, 0.f, 0.f, 0.f};
#pragma unroll
  for (int kk = 0; kk < 2; ++kk) {
    const int ck = kk * 4 + l4;
    const int r1 = 32 + nw + l15;
    const int r0 = 32 - d + nw + l15;
    const bf8_t b1 = *reinterpret_cast<const bf8_t*>(&xwS[r1 * 64 + (ck ^ (r1 & 7)) * 8]);
    const bf8_t b0 = *reinterpret_cast<const bf8_t*>(&xwS[r0 * 64 + (ck ^ (r0 & 7)) * 8]);
#pragma unroll
    for (int mi = 0; mi < 8; ++mi) {
      const int rw1 = 128 + mi * 16 + l15;   // tap1 rows
      const bf8_t a1 = *reinterpret_cast<const bf8_t*>(&WcS[rw1 * 64 + (ck ^ (rw1 & 7)) * 8]);
      acc[mi] = __builtin_amdgcn_mfma_f32_16x16x32_bf16(a1, b1, acc[mi], 0, 0, 0);
      const int rw0 = mi * 16 + l15;         // tap0 rows
      const bf8_t a0 = *reinterpret_cast<const bf8_t*>(&WcS[rw0 * 64 + (ck ^ (rw0 & 7)) * 8]);
      acc[mi] = __builtin_amdgcn_mfma_f32_16x16x32_bf16(a0, b0, acc[mi], 0, 0, 0);
    }
  }

  // gate -> gtS (own-lane row, swizzled slots)
  const int t_lane = t0 + nw + l15;
  const int ci = (t_lane >= (c0 + 1) * 75) ? 1 : 0;
  const int grow = nw + l15;
#pragma unroll
  for (int mi = 0; mi < 4; ++mi) {
    float gg[4];
#pragma unroll
    for (int r = 0; r < 4; ++r) {
      const int olo = mi * 16 + l4 * 4 + r;
      gg[r] = fast_gate(acc[mi][r] + cnd[ci][olo], acc[mi + 4][r] + cnd[ci][olo + 64]);
    }
    const int hb = mi * 16 + l4 * 4;
    const int ch = hb >> 3, off = hb & 7;
    unsigned short* gp = &gtS[grow * 64 + (ch ^ (grow & 7)) * 8 + off];
    *reinterpret_cast<unsigned*>(gp) = (unsigned)f2bu(gg[0]) | ((unsigned)f2bu(gg[1]) << 16);
    *reinterpret_cast<unsigned*>(gp + 2) = (unsigned)f2bu(gg[2]) | ((unsigned)f2bu(gg[3]) << 16);
  }

  // g -> gbuf: positional copy of swizzled gtS == pre-swizzled layout skip expects
  {
    unsigned short* gb = gbuf + ((size_t)layer * kNS + b * kS + t0) * 64;
#pragma unroll
    for (int r = 0; r < 2; ++r) {
      const int q = lane * 2 + r;
      const int row = nw + (q >> 3), c = q & 7;
      *reinterpret_cast<uint4*>(gb + (size_t)row * 64 + c * 8) =
          *reinterpret_cast<const uint4*>(&gtS[row * 64 + c * 8]);
    }
  }

  if (write_x) {
    // res GEMM: A-frags from registers, B-frags own-lane row of gtS
    f4_t accr[4];
#pragma unroll
    for (int i = 0; i < 4; ++i) accr[i] = (f4_t){0.f, 0.f, 0.f, 0.f};
#pragma unroll
    for (int kk = 0; kk < 2; ++kk) {
      const int ck = kk * 4 + l4;
      const bf8_t bfr = *reinterpret_cast<const bf8_t*>(&gtS[grow * 64 + (ck ^ (grow & 7)) * 8]);
#pragma unroll
      for (int mi = 0; mi < 4; ++mi)
        accr[mi] = __builtin_amdgcn_mfma_f32_16x16x32_bf16(wrr[kk][mi], bfr, accr[mi], 0, 0, 0);
    }
    // x' = accr + rb + x_in -> overwrite own gtS row (g already flushed to gbuf)
    const int xrow = 32 + grow;
#pragma unroll
    for (int mi = 0; mi < 4; ++mi) {
      const int h0 = mi * 16 + l4 * 4;
      const int ch = h0 >> 3, off = h0 & 7;
      const unsigned short* xp = &xwS[xrow * 64 + (ch ^ (xrow & 7)) * 8 + off];
      const unsigned u01 = *reinterpret_cast<const unsigned*>(xp);
      const unsigned u23 = *reinterpret_cast<const unsigned*>(xp + 2);
      const float x0 = accr[mi][0] + rbv[mi].x + b2f((unsigned short)(u01 & 0xffffu));
      const float x1 = accr[mi][1] + rbv[mi].y + b2f((unsigned short)(u01 >> 16));
      const float x2 = accr[mi][2] + rbv[mi].z + b2f((unsigned short)(u23 & 0xffffu));
      const float x3 = accr[mi][3] + rbv[mi].w + b2f((unsigned short)(u23 >> 16));
      unsigned short* gp = &gtS[grow * 64 + (ch ^ (grow & 7)) * 8 + off];
      *reinterpret_cast<unsigned*>(gp) = (unsigned)f2bu(x0) | ((unsigned)f2bu(x1) << 16);
      *reinterpret_cast<unsigned*>(gp + 2) = (unsigned)f2bu(x2) | ((unsigned)f2bu(x3) << 16);
    }
    // x_out write (wave-private rows, unswizzle on read), 2KB contiguous per wave
    unsigned short* xob = x_out + ((size_t)b * kXR + kGR + t0) * 64;
#pragma unroll
    for (int r = 0; r < 2; ++r) {
      const int q = lane * 2 + r;
      const int row = nw + (q >> 3), c = q & 7, slot = c ^ (row & 7);
      *reinterpret_cast<uint4*>(xob + (size_t)row * 64 + c * 8) =
          *reinterpret_cast<const uint4*>(&gtS[row * 64 + slot * 8]);
    }
  }
}

// ------- skip GEMM v4 (unchanged): 600x512, 64n x 256o, coalesced fragment B ---------
__global__ __launch_bounds__(512) void skip_kernel(
    const unsigned short* __restrict__ gbuf, const unsigned short* __restrict__ swb2,
    const float* __restrict__ bs, unsigned short* __restrict__ skipb) {
  const int n0 = blockIdx.x * 64;
  __shared__ alignas(16) unsigned short Ag[2][128][64];
  const int tid = threadIdx.x, lane = tid & 63, wv = tid >> 6;
  const int l15 = lane & 15, l4 = lane >> 4;
  const int ow = wv * 32;
  f4_t acc[4][2];
#pragma unroll
  for (int i = 0; i < 4; ++i)
#pragma unroll
    for (int j = 0; j < 2; ++j) acc[i][j] = (f4_t){0.f, 0.f, 0.f, 0.f};

#define STAGE2(kb2, buf)                                                               \
  {                                                                                    \
    const unsigned short* s0 =                                                         \
        gbuf + ((size_t)((kb2)*2) * kNS + n0) * 64 + (size_t)tid * 8;                  \
    const unsigned short* s1 =                                                         \
        gbuf + ((size_t)((kb2)*2 + 1) * kNS + n0) * 64 + (size_t)tid * 8;              \
    __builtin_amdgcn_global_load_lds(                                                  \
        (const __attribute__((address_space(1))) unsigned int*)s0,                     \
        (__attribute__((address_space(3))) unsigned int*)(&Ag[buf][wv * 8][0]),        \
        16, 0, 0);                                                                     \
    __builtin_amdgcn_global_load_lds(                                                  \
        (const __attribute__((address_space(1))) unsigned int*)s1,                     \
        (__attribute__((address_space(3))) unsigned int*)(&Ag[buf][64 + wv * 8][0]),   \
        16, 0, 0);                                                                     \
  }

  STAGE2(0, 0);
  for (int kb2 = 0; kb2 < 12; ++kb2) {
    __syncthreads();
    if (kb2 < 11) STAGE2(kb2 + 1, (kb2 + 1) & 1);
    const int bi = kb2 & 1;
#pragma unroll
    for (int sub = 0; sub < 2; ++sub) {
      const int kb = kb2 * 2 + sub;
#pragma unroll
      for (int kk = 0; kk < 2; ++kk) {
        bf8_t afr[4], bfr[2];
#pragma unroll
        for (int i = 0; i < 4; ++i) {
          const int row = i * 16 + l15;
          const int slot = (kk * 4 + l4) ^ (row & 7);
          afr[i] = *reinterpret_cast<const bf8_t*>(&Ag[bi][sub * 64 + row][slot << 3]);
        }
#pragma unroll
        for (int j = 0; j < 2; ++j)
          bfr[j] = *reinterpret_cast<const bf8_t*>(
              swb2 + ((size_t)(kb * 2 + kk) * 256 + ow + j * 16 + l15) * 32 + l4 * 8);
#pragma unroll
        for (int mi = 0; mi < 4; ++mi)
#pragma unroll
          for (int ni = 0; ni < 2; ++ni)
            acc[mi][ni] = __builtin_amdgcn_mfma_f32_16x16x32_bf16(afr[mi], bfr[ni],
                                                                  acc[mi][ni], 0, 0, 0);
      }
    }
  }
#undef STAGE2
#pragma unroll
  for (int mi = 0; mi < 4; ++mi)
#pragma unroll
    for (int ni = 0; ni < 2; ++ni) {
      const int o = ow + ni * 16 + l15;
      const float bo = bs[o];
#pragma unroll
      for (int r = 0; r < 4; ++r) {
        const int n = n0 + mi * 16 + l4 * 4 + r;
        skipb[(size_t)n * 256 + o] = f2bu(acc[mi][ni][r] + bo);
      }
    }
}

// ---------------- head (unchanged): relu -> W1 -> relu -> W2 -> log_softmax ----------
__device__ inline unsigned int relu2(unsigned int u) {
  const unsigned lo = (u & 0x8000u) ? 0u : (u & 0xFFFFu);
  const unsigned hi = (u & 0x80000000u) ? 0u : (u & 0xFFFF0000u);
  return lo | hi;
}

__global__ __launch_bounds__(256) void head_kernel(
    const unsigned short* __restrict__ skipb, const unsigned short* __restrict__ w1f,
    const unsigned short* __restrict__ w2f, float* __restrict__ out) {
  const int b = blockIdx.y;
  const int t0 = blockIdx.x * 32;
  const int n0 = b * kS + t0;
  __shared__ __align__(16) char smem[16896 * 2];
  __shared__ float lsa[32];
  unsigned short (*A1)[264] = reinterpret_cast<unsigned short(*)[264]>(smem);
  unsigned short (*H1)[264] = reinterpret_cast<unsigned short(*)[264]>(smem + 16896);
  float (*LG)[260] = reinterpret_cast<float(*)[260]>(smem);

  const int tid = threadIdx.x, lane = tid & 63, wv = tid >> 6;
  const int l15 = lane & 15, l4 = lane >> 4;
  for (int r = 0; r < 4; ++r) {
    const int ch = r * 256 + tid;
    const int row = ch >> 5, c8 = (ch & 31) << 3;
    uint4 v = *reinterpret_cast<const uint4*>(skipb + (size_t)(n0 + row) * 256 + c8);
    v.x = relu2(v.x); v.y = relu2(v.y); v.z = relu2(v.z); v.w = relu2(v.w);
    *reinterpret_cast<uint4*>(&A1[row][c8]) = v;
  }
  __syncthreads();
  f4_t a1[2][4];
#pragma unroll
  for (int i = 0; i < 2; ++i)
#pragma unroll
    for (int j = 0; j < 4; ++j) a1[i][j] = (f4_t){0.f, 0.f, 0.f, 0.f};
  for (int kk = 0; kk < 8; ++kk) {
    const int ko = kk * 32 + l4 * 8;
    bf8_t afr[2], bfr[4];
#pragma unroll
    for (int i = 0; i < 2; ++i)
      afr[i] = *reinterpret_cast<const bf8_t*>(&A1[i * 16 + l15][ko]);
#pragma unroll
    for (int j = 0; j < 4; ++j)
      bfr[j] = *reinterpret_cast<const bf8_t*>(
          w1f + ((size_t)kk * 256 + wv * 64 + j * 16 + l15) * 32 + l4 * 8);
#pragma unroll
    for (int mi = 0; mi < 2; ++mi)
#pragma unroll
      for (int ni = 0; ni < 4; ++ni)
        a1[mi][ni] = __builtin_amdgcn_mfma_f32_16x16x32_bf16(afr[mi], bfr[ni],
                                                             a1[mi][ni], 0, 0, 0);
  }
#pragma unroll
  for (int mi = 0; mi < 2; ++mi)
#pragma unroll
    for (int ni = 0; ni < 4; ++ni)
#pragma unroll
      for (int r = 0; r < 4; ++r)
        H1[mi * 16 + l4 * 4 + r][wv * 64 + ni * 16 + l15] =
            f2bu(fmaxf(a1[mi][ni][r], 0.f));
  __syncthreads();
  f4_t a2[2][4];
#pragma unroll
  for (int i = 0; i < 2; ++i)
#pragma unroll
    for (int j = 0; j < 4; ++j) a2[i][j] = (f4_t){0.f, 0.f, 0.f, 0.f};
  for (int kk = 0; kk < 8; ++kk) {
    const int ko = kk * 32 + l4 * 8;
    bf8_t afr[2], bfr[4];
#pragma unroll
    for (int i = 0; i < 2; ++i)
      afr[i] = *reinterpret_cast<const bf8_t*>(&H1[i * 16 + l15][ko]);
#pragma unroll
    for (int j = 0; j < 4; ++j)
      bfr[j] = *reinterpret_cast<const bf8_t*>(
          w2f + ((size_t)kk * 256 + wv * 64 + j * 16 + l15) * 32 + l4 * 8);
#pragma unroll
    for (int mi = 0; mi < 2; ++mi)
#pragma unroll
      for (int ni = 0; ni < 4; ++ni)
        a2[mi][ni] = __builtin_amdgcn_mfma_f32_16x16x32_bf16(afr[mi], bfr[ni],
                                                             a2[mi][ni], 0, 0, 0);
  }
  __syncthreads();
#pragma unroll
  for (int mi = 0; mi < 2; ++mi)
#pragma unroll
    for (int ni = 0; ni < 4; ++ni)
#pragma unroll
      for (int r = 0; r < 4; ++r)
        LG[mi * 16 + l4 * 4 + r][wv * 64 + ni * 16 + l15] = a2[mi][ni][r];
  __syncthreads();
  const int rn = tid >> 3, s = tid & 7;
  float m = -3.4e38f;
  for (int a = s; a < 256; a += 8) m = fmaxf(m, LG[rn][a]);
  m = fmaxf(m, __shfl_xor(m, 1));
  m = fmaxf(m, __shfl_xor(m, 2));
  m = fmaxf(m, __shfl_xor(m, 4));
  float sum = 0.f;
  for (int a = s; a < 256; a += 8) sum += __expf(LG[rn][a] - m);
  sum += __shfl_xor(sum, 1);
  sum += __shfl_xor(sum, 2);
  sum += __shfl_xor(sum, 4);
  if (s == 0) lsa[rn] = m + __logf(sum);
  __syncthreads();
  float* ob = out + (size_t)b * kA * kS + t0;
  for (int q = 0; q < 8; ++q) {
    const int a = q * 32 + (tid >> 3);
    const int t4 = (tid & 7) * 4;
    float4 v;
    v.x = LG[t4 + 0][a] - lsa[t4 + 0];
    v.y = LG[t4 + 1][a] - lsa[t4 + 1];
    v.z = LG[t4 + 2][a] - lsa[t4 + 2];
    v.w = LG[t4 + 3][a] - lsa[t4 + 3];
    *reinterpret_cast<float4*>(ob + (size_t)a * kS + t4) = v;
  }
}

}  // namespace

extern "C" void kernel_launch(void* const* d_in, const int* in_sizes, int n_in,
                              void* d_out, int out_size, void* d_ws, size_t ws_size,
                              hipStream_t stream) {
  const float* lf  = (const float*)d_in[0];
  const float* sig = (const float*)d_in[1];
  const float* ew  = (const float*)d_in[2];
  const float* eb  = (const float*)d_in[3];
  const float* tw  = (const float*)d_in[4];
  const float* tb  = (const float*)d_in[5];
  const float* cw  = (const float*)d_in[6];
  const float* cb  = (const float*)d_in[7];
  const float* dw  = (const float*)d_in[8];
  const float* dbf = (const float*)d_in[9];
  const float* rw  = (const float*)d_in[10];
  const float* rb  = (const float*)d_in[11];
  const float* sw  = (const float*)d_in[12];
  const float* sb  = (const float*)d_in[13];
  const float* w1  = (const float*)d_in[14];
  const float* w2  = (const float*)d_in[15];
  float* out = (float*)d_out;

  char* p = (char*)d_ws;
  float* cond = (float*)p;            p += (size_t)kB * kT4 * 3072 * 4;
  unsigned short* xA = (unsigned short*)p;    p += (size_t)kB * kXR * 64 * 2;
  unsigned short* xB = (unsigned short*)p;    p += (size_t)kB * kXR * 64 * 2;
  unsigned short* gbuf = (unsigned short*)p;  p += (size_t)kNL * kNS * 64 * 2;
  unsigned short* skipb = (unsigned short*)p; p += (size_t)kNS * 256 * 2;
  unsigned short* wcb = (unsigned short*)p;   p += (size_t)kNL * 2 * 128 * 64 * 2;
  unsigned short* wrf = (unsigned short*)p;   p += (size_t)(kNL - 1) * 64 * 64 * 2;
  unsigned short* swb2 = (unsigned short*)p;  p += (size_t)256 * kK * 2;
  unsigned short* w1f = (unsigned short*)p;   p += (size_t)256 * 256 * 2;
  unsigned short* w2f = (unsigned short*)p;   p += (size_t)256 * 256 * 2;
  float* bs = (float*)p;              p += 1024;
  float* cwT = (float*)p;             p += (size_t)80 * 3072 * 4;
  float* W2 = (float*)p;              p += (size_t)4 * 80 * 3072 * 4;
  float* bias2 = (float*)p;           p += (size_t)3072 * 4;

  const int prep_n = 393216 + 94208 + 393216 + 65536 + 65536 + 245760;
  prep_kernel<<<(prep_n + 255) / 256, 256, 0, stream>>>(dw, rw, sw, w1, w2, cw,
                                                        wcb, wrf, swb2, w1f, w2f, cwT);
  prep_w2_kernel<<<dim3(12, 4), 256, 0, stream>>>(tw, cwT, W2);
  bias2_kernel<<<12, 256, 0, stream>>>(cwT, tb, cb, dbf, bias2);
  cond_gemm_kernel<<<dim3(48, 4, 2), 256, 0, stream>>>(lf, W2, bias2, cond);
  bias_sum_kernel<<<1, 256, 0, stream>>>(sb, bs);
  embed_kernel<<<(kB * kXR * 8 + 255) / 256, 256, 0, stream>>>(sig, ew, eb, xA, xB);

  unsigned short* xcur = xA;
  unsigned short* xnxt = xB;
  for (int l = 0; l < kNL; ++l) {
    const int d = 1 << (l % 6);
    const int wx = (l < kNL - 1) ? 1 : 0;
    layer_kernel<<<dim3(300, 2), 256, 0, stream>>>(
        xcur, xnxt, wcb + (size_t)l * 16384, wrf + (size_t)(wx ? l : 0) * 4096,
        cond, rb + (size_t)(wx ? l : 0) * 64, gbuf, l, d, wx);
    if (wx) { unsigned short* tmp = xcur; xcur = xnxt; xnxt = tmp; }
  }
  skip_kernel<<<600, 512, 0, stream>>>(gbuf, swb2, bs, skipb);
  head_kernel<<<dim3(600, 2), 256, 0, stream>>>(skipb, w1f, w2f, out);
}